// Round 11
// baseline (629.586 us; speedup 1.0000x reference)
//
#include <hip/hip_runtime.h>
#include <cstdint>

#define NPTS 65536
#define NS 16
#define EPSV 1e-5f

typedef __attribute__((ext_vector_type(8))) short bf16x8;
typedef __attribute__((ext_vector_type(8))) unsigned short u16x8;
typedef __attribute__((ext_vector_type(4))) float f32x4;
typedef __attribute__((ext_vector_type(4))) unsigned int u32x4;
union FragU { u32x4 u; bf16x8 h; };

// per-layer stats block (512 floats each)
#define SUM1 0
#define SSQ1 64
#define SUM2 128
#define SSQ2 192
#define SUM3 256
#define SSQ3 320
// wfold region (floats)
#define WKAOF 0
#define WQBAOF 4096
#define BKAOF 8192
#define BQBAOF 8256
#define WFOLD_FLOATS 8320

// truncation split of two floats into packed bf16 hi-pair / lo-pair (v_perm based).
__device__ __forceinline__ void split2(float e0, float e1, unsigned int& hi, unsigned int& lo) {
    unsigned int u0 = __float_as_uint(e0), u1 = __float_as_uint(e1);
    hi = __builtin_amdgcn_perm(u1, u0, 0x07060302u);
    float l0f = e0 - __uint_as_float(u0 & 0xFFFF0000u);
    float l1f = e1 - __uint_as_float(u1 & 0xFFFF0000u);
    lo = __builtin_amdgcn_perm(__float_as_uint(l1f), __float_as_uint(l0f), 0x07060302u);
}

// fp32 -> bf16 round-to-nearest(-even-ish)
__device__ __forceinline__ unsigned short f2bf(float x) {
    unsigned int u = __float_as_uint(x);
    u += 0x7FFFu + ((u >> 16) & 1u);
    return (unsigned short)(u >> 16);
}
__device__ __forceinline__ float bf2f(unsigned short h) {
    return __uint_as_float(((unsigned int)h) << 16);
}

__global__ void k_mask(const uint32_t* emp32, uint8_t* mask) {
    int bad = 0;
    for (int w = threadIdx.x; w < 1024; w += 256) bad |= (emp32[w] > 1u) ? 1 : 0;
    __shared__ int sbad[4];
    unsigned long long b = __ballot(bad != 0);
    if ((threadIdx.x & 63) == 0) sbad[threadIdx.x >> 6] = (b != 0ull) ? 1 : 0;
    __syncthreads();
    int flag = sbad[0] | sbad[1] | sbad[2] | sbad[3];
    int i = blockIdx.x * 256 + threadIdx.x;
    uint8_t mv;
    if (flag) mv = (((const uint8_t*)emp32)[i] != 0);
    else      mv = (emp32[i] != 0u);
    mask[i] = mv;
}

// Folded weights: Wka = wk @ A, Wqba = wq @ (B-A); biases likewise.
__global__ void k0(const float* wq, const float* bq, const float* wk, const float* bk,
                   const float* w1, float* wfold, int cin) {
    int f = threadIdx.x;
    int c = blockIdx.x;
    float a = 0.f, q = 0.f;
    for (int d = 0; d < 64; d++) {
        float A  = w1[d*64 + f];
        float Bm = w1[(67+d)*64 + f] - A;
        a = fmaf(wk[c*64 + d], A,  a);
        q = fmaf(wq[c*64 + d], Bm, q);
    }
    wfold[WKAOF  + c*64 + f] = a;
    wfold[WQBAOF + c*64 + f] = q;
    if (c == 0) {
        float ba = 0.f, bqv = 0.f;
        for (int d = 0; d < 64; d++) {
            float A  = w1[d*64 + f];
            float Bm = w1[(67+d)*64 + f] - A;
            ba  = fmaf(bk[d], A,  ba);
            bqv = fmaf(bq[d], Bm, bqv);
        }
        wfold[BKAOF  + f] = ba;
        wfold[BQBAOF + f] = bqv;
    }
}

// MFMA k1: [KA|QBA](n,128) = prebn(feats) @ Wcat(cin,128) + xyz @ Axyz(3,128) + bias.
// KA stored as bf16 (natural layout, 128B rows); QBA fp32 natural.
template<int CIN, bool PREBN>
__global__ void __launch_bounds__(256) k1m(const float* __restrict__ feats, const float* __restrict__ xyz,
                    const float* __restrict__ w1, const float* __restrict__ wfold,
                    const float* __restrict__ statsPrev, const float* __restrict__ goP,
                    const float* __restrict__ boP,
                    unsigned short* __restrict__ KAb, float* __restrict__ QBA) {
    const int l = threadIdx.x & 63;
    const int wv = threadIdx.x >> 6;
    const int sidx = l & 15;
    const int g = l >> 4;
    const int col = sidx;
    constexpr int NT = (CIN == 64) ? 2 : 1;

    unsigned int bh[NT][2][4], bl[NT][2][4];
    #pragma unroll
    for (int t = 0; t < NT; t++)
    #pragma unroll
    for (int fl = 0; fl < 2; fl++) {
        int f128 = (wv*2 + fl)*16 + col;
        const float* W = (f128 < 64) ? (wfold + WKAOF) : (wfold + WQBAOF);
        int f = (f128 < 64) ? f128 : f128 - 64;
        #pragma unroll
        for (int r = 0; r < 4; r++) {
            int c0 = t*32 + g*8 + 2*r;
            float e0 = 0.f, e1 = 0.f;
            if (CIN == 64 || g < 2) {
                e0 = W[c0*64 + f];
                e1 = W[(c0+1)*64 + f];
            }
            split2(e0, e1, bh[t][fl][r], bl[t][fl][r]);
        }
    }
    unsigned int xbh[2][4], xbl[2][4];
    float biasf[2];
    #pragma unroll
    for (int fl = 0; fl < 2; fl++) {
        int f128 = (wv*2 + fl)*16 + col;
        float A0, A1, A2;
        if (f128 < 64) {
            A0 = w1[64*64 + f128]; A1 = w1[65*64 + f128]; A2 = w1[66*64 + f128];
            biasf[fl] = wfold[BKAOF + f128];
        } else {
            int f = f128 - 64;
            A0 = w1[131*64 + f] - w1[64*64 + f];
            A1 = w1[132*64 + f] - w1[65*64 + f];
            A2 = w1[133*64 + f] - w1[66*64 + f];
            biasf[fl] = wfold[BQBAOF + f];
        }
        split2(A0, A1, xbh[fl][0], xbl[fl][0]);
        split2(A2, 0.f, xbh[fl][1], xbl[fl][1]);
        xbh[fl][2] = 0; xbh[fl][3] = 0; xbl[fl][2] = 0; xbl[fl][3] = 0;
    }
    float scP[NT*8], shP[NT*8];
    if (PREBN) {
        const float invN = 1.0f / (float)NPTS;
        #pragma unroll
        for (int t = 0; t < NT; t++)
        #pragma unroll
        for (int i = 0; i < 8; i++) {
            int c = t*32 + g*8 + i;
            float m = statsPrev[SUM3 + c] * invN;
            float v = fmaxf(statsPrev[SSQ3 + c] * invN - m*m, 0.0f);
            float s = goP[c] * rsqrtf(v + EPSV);
            scP[t*8+i] = s;
            shP[t*8+i] = fmaf(-m, s, boP[c]);
        }
    }

    for (int tile = blockIdx.x; tile < NPTS/16; tile += gridDim.x) {
        int p = tile*16 + sidx;
        unsigned int ahu[NT][4], alu[NT][4];
        #pragma unroll
        for (int t = 0; t < NT; t++) {
            float xv[8];
            if (CIN == 64) {
                f32x4 a0 = *(const f32x4*)(feats + (size_t)p*64 + t*32 + g*8);
                f32x4 a1 = *(const f32x4*)(feats + (size_t)p*64 + t*32 + g*8 + 4);
                #pragma unroll
                for (int i = 0; i < 4; i++) { xv[i] = a0[i]; xv[4+i] = a1[i]; }
                if (PREBN) {
                    #pragma unroll
                    for (int i = 0; i < 8; i++)
                        xv[i] = fmaxf(fmaf(scP[t*8+i], xv[i], shP[t*8+i]), 0.0f);
                }
            } else {
                if (g < 2) {
                    f32x4 a0 = *(const f32x4*)(feats + (size_t)p*16 + g*8);
                    f32x4 a1 = *(const f32x4*)(feats + (size_t)p*16 + g*8 + 4);
                    #pragma unroll
                    for (int i = 0; i < 4; i++) { xv[i] = a0[i]; xv[4+i] = a1[i]; }
                } else {
                    #pragma unroll
                    for (int i = 0; i < 8; i++) xv[i] = 0.f;
                }
            }
            #pragma unroll
            for (int r = 0; r < 4; r++) split2(xv[2*r], xv[2*r+1], ahu[t][r], alu[t][r]);
        }
        unsigned int xah[4] = {0,0,0,0}, xal[4] = {0,0,0,0};
        if (g == 0) {
            float x0 = xyz[p*3], x1 = xyz[p*3+1], x2 = xyz[p*3+2];
            split2(x0, x1, xah[0], xal[0]);
            split2(x2, 0.f, xah[1], xal[1]);
        }
        f32x4 acc[2];
        #pragma unroll
        for (int fl = 0; fl < 2; fl++)
            acc[fl] = (f32x4){biasf[fl], biasf[fl], biasf[fl], biasf[fl]};
        #pragma unroll
        for (int t = 0; t < NT; t++) {
            FragU ah, al;
            ah.u = (u32x4){ahu[t][0], ahu[t][1], ahu[t][2], ahu[t][3]};
            al.u = (u32x4){alu[t][0], alu[t][1], alu[t][2], alu[t][3]};
            #pragma unroll
            for (int fl = 0; fl < 2; fl++) {
                FragU Bh, Bl;
                Bh.u = (u32x4){bh[t][fl][0], bh[t][fl][1], bh[t][fl][2], bh[t][fl][3]};
                Bl.u = (u32x4){bl[t][fl][0], bl[t][fl][1], bl[t][fl][2], bl[t][fl][3]};
                acc[fl] = __builtin_amdgcn_mfma_f32_16x16x32_bf16(ah.h, Bh.h, acc[fl], 0, 0, 0);
                acc[fl] = __builtin_amdgcn_mfma_f32_16x16x32_bf16(ah.h, Bl.h, acc[fl], 0, 0, 0);
                acc[fl] = __builtin_amdgcn_mfma_f32_16x16x32_bf16(al.h, Bh.h, acc[fl], 0, 0, 0);
            }
        }
        {
            FragU ah, al;
            ah.u = (u32x4){xah[0], xah[1], xah[2], xah[3]};
            al.u = (u32x4){xal[0], xal[1], xal[2], xal[3]};
            #pragma unroll
            for (int fl = 0; fl < 2; fl++) {
                FragU Bh, Bl;
                Bh.u = (u32x4){xbh[fl][0], xbh[fl][1], xbh[fl][2], xbh[fl][3]};
                Bl.u = (u32x4){xbl[fl][0], xbl[fl][1], xbl[fl][2], xbl[fl][3]};
                acc[fl] = __builtin_amdgcn_mfma_f32_16x16x32_bf16(ah.h, Bh.h, acc[fl], 0, 0, 0);
                acc[fl] = __builtin_amdgcn_mfma_f32_16x16x32_bf16(ah.h, Bl.h, acc[fl], 0, 0, 0);
                acc[fl] = __builtin_amdgcn_mfma_f32_16x16x32_bf16(al.h, Bh.h, acc[fl], 0, 0, 0);
            }
        }
        #pragma unroll
        for (int fl = 0; fl < 2; fl++) {
            int f128 = (wv*2 + fl)*16 + col;
            #pragma unroll
            for (int r = 0; r < 4; r++) {
                int po = tile*16 + g*4 + r;
                float v = acc[fl][r];
                if (f128 < 64) KAb[(size_t)po*64 + f128] = f2bf(v);
                else           QBA[(size_t)po*64 + (f128-64)] = v;
            }
        }
    }
}

// k2: stats of y1 over (n,s). Batch-4 bf16-KA gather (2x16B/row/lane, full lines).
__global__ void __launch_bounds__(256) k2(const unsigned short* __restrict__ KAb, const float* __restrict__ QBA,
                   const int* __restrict__ knn, const uint8_t* __restrict__ mask, float* stats) {
    const int l = threadIdx.x & 63;
    const int wv = threadIdx.x >> 6;
    const int s = l & 15;
    const int g = l >> 4;
    float s0[16], s1[16];
    #pragma unroll
    for (int i = 0; i < 16; i++) { s0[i] = 0.f; s1[i] = 0.f; }

    const int STR = gridDim.x * 16;
    for (int n0 = blockIdx.x * 16 + wv*4; n0 < NPTS; n0 += STR) {
        bool msk[4];
        u16x8 ka[4][2];
        #pragma unroll
        for (int u = 0; u < 4; u++) {
            int n = n0 + u;
            msk[u] = (mask[n] != 0);
            if (!msk[u]) {
                int j = knn[n*16 + s];
                const unsigned short* kp = KAb + (size_t)j*64;
                ka[u][0] = *(const u16x8*)(kp + g*8);
                ka[u][1] = *(const u16x8*)(kp + 32 + g*8);
            }
        }
        #pragma unroll
        for (int u = 0; u < 4; u++) {
            if (msk[u]) continue;
            int n = n0 + u;
            const float* qp = QBA + (size_t)n*64;
            f32x4 q0 = *(const f32x4*)(qp + g*8);
            f32x4 q1 = *(const f32x4*)(qp + g*8 + 4);
            f32x4 q2 = *(const f32x4*)(qp + 32 + g*8);
            f32x4 q3 = *(const f32x4*)(qp + 32 + g*8 + 4);
            #pragma unroll
            for (int t = 0; t < 2; t++)
            #pragma unroll
            for (int i = 0; i < 8; i++) {
                float kf = bf2f(ka[u][t][i]);
                float qv = t ? ((i < 4) ? q2[i] : q3[i-4])
                             : ((i < 4) ? q0[i] : q1[i-4]);
                float y = kf + qv;
                s0[t*8+i] += y;
                s1[t*8+i] = fmaf(y, y, s1[t*8+i]);
            }
        }
    }
    #pragma unroll
    for (int i = 0; i < 16; i++) {
        #pragma unroll
        for (int d = 1; d < 16; d <<= 1) {
            s0[i] += __shfl_xor(s0[i], d, 64);
            s1[i] += __shfl_xor(s1[i], d, 64);
        }
    }
    __shared__ float r0[4][64], r1[4][64];
    if (s == 0) {
        #pragma unroll
        for (int t = 0; t < 2; t++)
        #pragma unroll
        for (int i = 0; i < 8; i++) {
            int c = t*32 + g*8 + i;
            r0[wv][c] = s0[t*8+i];
            r1[wv][c] = s1[t*8+i];
        }
    }
    __syncthreads();
    int tid = threadIdx.x;
    if (tid < 64) {
        atomicAdd(&stats[SUM1 + tid], r0[0][tid]+r0[1][tid]+r0[2][tid]+r0[3][tid]);
        atomicAdd(&stats[SSQ1 + tid], r1[0][tid]+r1[1][tid]+r1[2][tid]+r1[3][tid]);
    }
}

// MFMA k4: batch-2 bf16-KA gather; w2 fragments in LDS (frees ~64 VGPR -> more waves).
// LDS layout: wlds[(idx*64 + lane)*4 + r], idx = t*8 + ft*2 + h  (canonical b128: uniform
// idx, consecutive lanes -> consecutive 16B, conflict-free).
__global__ void __launch_bounds__(256) k4(const unsigned short* __restrict__ KAb, const float* __restrict__ QBA,
                   const int* __restrict__ knn, const uint8_t* __restrict__ mask,
                   const float* __restrict__ w2, const float* __restrict__ g1, const float* __restrict__ b1,
                   float* stats, float* __restrict__ y2max, float* __restrict__ y2min) {
    const int l    = threadIdx.x & 63;
    const int wv   = threadIdx.x >> 6;
    const int sidx = l & 15;
    const int g    = l >> 4;
    const int col  = sidx;

    __shared__ unsigned int wlds[16*64*4];   // 16 KB
    __shared__ float red[8][64];

    float sc1v[16], sh1v[16];
    const float inv = 1.0f / ((float)NPTS * (float)NS);
    #pragma unroll
    for (int t = 0; t < 2; t++)
    #pragma unroll
    for (int i = 0; i < 8; i++) {
        int c = t*32 + g*8 + i;
        float m = stats[SUM1 + c] * inv;
        float v = fmaxf(stats[SSQ1 + c] * inv - m*m, 0.0f);
        float s = g1[c] * rsqrtf(v + EPSV);
        sc1v[t*8+i] = s;
        sh1v[t*8+i] = fmaf(-m, s, b1[c]);
    }

    // wave 0 computes w2 hi/lo fragments once for all waves (frags depend only on lane).
    if (threadIdx.x < 64) {
        #pragma unroll
        for (int t = 0; t < 2; t++)
        #pragma unroll
        for (int ft = 0; ft < 4; ft++) {
            unsigned int wh[4], wl[4];
            #pragma unroll
            for (int r = 0; r < 4; r++) {
                int k0i = t*32 + g*8 + 2*r;
                split2(w2[k0i*64 + ft*16 + col], w2[(k0i+1)*64 + ft*16 + col], wh[r], wl[r]);
            }
            int idxh = t*8 + ft*2, idxl = idxh + 1;
            #pragma unroll
            for (int r = 0; r < 4; r++) {
                wlds[(idxh*64 + l)*4 + r] = wh[r];
                wlds[(idxl*64 + l)*4 + r] = wl[r];
            }
        }
    }
    __syncthreads();

    float s0t[4] = {0.f,0.f,0.f,0.f};
    float s1t[4] = {0.f,0.f,0.f,0.f};

    const int STR = gridDim.x * 8;
    for (int n0 = blockIdx.x * 8 + wv*2; n0 < NPTS; n0 += STR) {
        bool msk[2];
        u16x8 ka[2][2];
        #pragma unroll
        for (int u = 0; u < 2; u++) {
            int n = n0 + u;
            msk[u] = (mask[n] != 0);
            int j = knn[n*16 + sidx];
            const unsigned short* kp = KAb + (size_t)j*64;
            ka[u][0] = *(const u16x8*)(kp + g*8);
            ka[u][1] = *(const u16x8*)(kp + 32 + g*8);
        }
        #pragma unroll
        for (int u = 0; u < 2; u++) {
            int n = n0 + u;
            bool masked = msk[u];
            const float* qp = QBA + (size_t)n*64;
            f32x4 q0 = *(const f32x4*)(qp + g*8);
            f32x4 q1 = *(const f32x4*)(qp + g*8 + 4);
            f32x4 q2 = *(const f32x4*)(qp + 32 + g*8);
            f32x4 q3 = *(const f32x4*)(qp + 32 + g*8 + 4);

            float x[16];
            #pragma unroll
            for (int t = 0; t < 2; t++)
            #pragma unroll
            for (int i = 0; i < 8; i++) {
                float kf = bf2f(ka[u][t][i]);
                float qv = t ? ((i < 4) ? q2[i] : q3[i-4])
                             : ((i < 4) ? q0[i] : q1[i-4]);
                float y = masked ? 0.f : (kf + qv);
                x[t*8+i] = fmaxf(fmaf(sc1v[t*8+i], y, sh1v[t*8+i]), 0.0f);
            }

            unsigned int ahu[2][4], alu[2][4];
            #pragma unroll
            for (int t = 0; t < 2; t++)
            #pragma unroll
            for (int r = 0; r < 4; r++)
                split2(x[t*8 + 2*r], x[t*8 + 2*r + 1], ahu[t][r], alu[t][r]);

            f32x4 acc[4];
            #pragma unroll
            for (int ft = 0; ft < 4; ft++) acc[ft] = (f32x4){0.f,0.f,0.f,0.f};

            #pragma unroll
            for (int t = 0; t < 2; t++) {
                FragU ah, al;
                ah.u = (u32x4){ahu[t][0], ahu[t][1], ahu[t][2], ahu[t][3]};
                al.u = (u32x4){alu[t][0], alu[t][1], alu[t][2], alu[t][3]};
                #pragma unroll
                for (int ft = 0; ft < 4; ft++) {
                    // opaque offsets so LICM can't hoist the LDS reads into registers
                    unsigned int offh = ((t*8 + ft*2)*64 + l)*4;
                    unsigned int offl = offh + 256;
                    asm volatile("" : "+v"(offh));
                    asm volatile("" : "+v"(offl));
                    FragU Bh, Bl;
                    Bh.u = *(const u32x4*)&wlds[offh];
                    Bl.u = *(const u32x4*)&wlds[offl];
                    acc[ft] = __builtin_amdgcn_mfma_f32_16x16x32_bf16(ah.h, Bh.h, acc[ft], 0, 0, 0);
                    acc[ft] = __builtin_amdgcn_mfma_f32_16x16x32_bf16(ah.h, Bl.h, acc[ft], 0, 0, 0);
                    acc[ft] = __builtin_amdgcn_mfma_f32_16x16x32_bf16(al.h, Bh.h, acc[ft], 0, 0, 0);
                }
            }

            float tmax[4], tmin[4];
            #pragma unroll
            for (int ft = 0; ft < 4; ft++) {
                f32x4 d = acc[ft];
                float lmax = fmaxf(fmaxf(d[0], d[1]), fmaxf(d[2], d[3]));
                float lmin = fminf(fminf(d[0], d[1]), fminf(d[2], d[3]));
                s0t[ft] += (d[0] + d[1]) + (d[2] + d[3]);
                s1t[ft] += fmaf(d[0],d[0], fmaf(d[1],d[1], fmaf(d[2],d[2], d[3]*d[3])));
                lmax = fmaxf(lmax, __shfl_xor(lmax, 16, 64));
                lmax = fmaxf(lmax, __shfl_xor(lmax, 32, 64));
                lmin = fminf(lmin, __shfl_xor(lmin, 16, 64));
                lmin = fminf(lmin, __shfl_xor(lmin, 32, 64));
                tmax[ft] = lmax; tmin[ft] = lmin;
            }
            float mx = (g==0) ? tmax[0] : (g==1) ? tmax[1] : (g==2) ? tmax[2] : tmax[3];
            float mn = (g==0) ? tmin[0] : (g==1) ? tmin[1] : (g==2) ? tmin[2] : tmin[3];
            y2max[(size_t)n*64 + l] = mx;
            y2min[(size_t)n*64 + l] = mn;
        }
    }

    #pragma unroll
    for (int ft = 0; ft < 4; ft++) {
        s0t[ft] += __shfl_xor(s0t[ft], 16, 64);
        s0t[ft] += __shfl_xor(s0t[ft], 32, 64);
        s1t[ft] += __shfl_xor(s1t[ft], 16, 64);
        s1t[ft] += __shfl_xor(s1t[ft], 32, 64);
    }
    float myS0 = (g==0) ? s0t[0] : (g==1) ? s0t[1] : (g==2) ? s0t[2] : s0t[3];
    float myS1 = (g==0) ? s1t[0] : (g==1) ? s1t[1] : (g==2) ? s1t[2] : s1t[3];
    red[wv][l] = myS0;
    red[4+wv][l] = myS1;
    __syncthreads();
    if (wv == 0) {
        atomicAdd(&stats[SUM2 + l], red[0][l]+red[1][l]+red[2][l]+red[3][l]);
        atomicAdd(&stats[SSQ2 + l], red[4][l]+red[5][l]+red[6][l]+red[7][l]);
    }
}

// MFMA k5: m = relu(bn2(max/min)); y3 = m @ wo; stats3.  y2min read only if any
// channel has negative bn2 scale (wave-uniform ballot).
__global__ void __launch_bounds__(256) k5m(const float* __restrict__ y2max, const float* __restrict__ y2min,
                    const float* __restrict__ wo, const float* __restrict__ g2, const float* __restrict__ b2,
                    float* stats, float* __restrict__ y3) {
    const int l = threadIdx.x & 63;
    const int wv = threadIdx.x >> 6;
    const int sidx = l & 15;
    const int g = l >> 4;
    const int ft = wv;

    unsigned int bh[2][4], bl[2][4];
    #pragma unroll
    for (int t = 0; t < 2; t++)
    #pragma unroll
    for (int r = 0; r < 4; r++) {
        int c0 = t*32 + g*8 + 2*r;
        split2(wo[c0*64 + ft*16 + sidx], wo[(c0+1)*64 + ft*16 + sidx], bh[t][r], bl[t][r]);
    }
    float sc2v[16], sh2v[16];
    const float inv = 1.0f / ((float)NPTS * (float)NS);
    int anyneg = 0;
    #pragma unroll
    for (int t = 0; t < 2; t++)
    #pragma unroll
    for (int i = 0; i < 8; i++) {
        int c = t*32 + g*8 + i;
        float m = stats[SUM2 + c] * inv;
        float v = fmaxf(stats[SSQ2 + c] * inv - m*m, 0.0f);
        float s = g2[c] * rsqrtf(v + EPSV);
        sc2v[t*8+i] = s;
        sh2v[t*8+i] = fmaf(-m, s, b2[c]);
        anyneg |= (s < 0.0f) ? 1 : 0;
    }
    const bool need_mn = (__ballot(anyneg != 0) != 0ull);

    float s0a = 0.f, s1a = 0.f;
    for (int tile = blockIdx.x; tile < NPTS/16; tile += gridDim.x) {
        int p = tile*16 + sidx;
        unsigned int ahu[2][4], alu[2][4];
        #pragma unroll
        for (int t = 0; t < 2; t++) {
            f32x4 mx0 = *(const f32x4*)(y2max + (size_t)p*64 + t*32 + g*8);
            f32x4 mx1 = *(const f32x4*)(y2max + (size_t)p*64 + t*32 + g*8 + 4);
            f32x4 mn0 = mx0, mn1 = mx1;
            if (need_mn) {
                mn0 = *(const f32x4*)(y2min + (size_t)p*64 + t*32 + g*8);
                mn1 = *(const f32x4*)(y2min + (size_t)p*64 + t*32 + g*8 + 4);
            }
            float mval[8];
            #pragma unroll
            for (int i = 0; i < 4; i++) {
                float sc = sc2v[t*8+i];
                float pre = (sc >= 0.f) ? mx0[i] : mn0[i];
                mval[i] = fmaxf(fmaf(sc, pre, sh2v[t*8+i]), 0.0f);
                float sc2 = sc2v[t*8+4+i];
                float pre2 = (sc2 >= 0.f) ? mx1[i] : mn1[i];
                mval[4+i] = fmaxf(fmaf(sc2, pre2, sh2v[t*8+4+i]), 0.0f);
            }
            #pragma unroll
            for (int r = 0; r < 4; r++) split2(mval[2*r], mval[2*r+1], ahu[t][r], alu[t][r]);
        }
        f32x4 acc = (f32x4){0.f,0.f,0.f,0.f};
        #pragma unroll
        for (int t = 0; t < 2; t++) {
            FragU ah, al, Bh, Bl;
            ah.u = (u32x4){ahu[t][0], ahu[t][1], ahu[t][2], ahu[t][3]};
            al.u = (u32x4){alu[t][0], alu[t][1], alu[t][2], alu[t][3]};
            Bh.u = (u32x4){bh[t][0], bh[t][1], bh[t][2], bh[t][3]};
            Bl.u = (u32x4){bl[t][0], bl[t][1], bl[t][2], bl[t][3]};
            acc = __builtin_amdgcn_mfma_f32_16x16x32_bf16(ah.h, Bh.h, acc, 0, 0, 0);
            acc = __builtin_amdgcn_mfma_f32_16x16x32_bf16(ah.h, Bl.h, acc, 0, 0, 0);
            acc = __builtin_amdgcn_mfma_f32_16x16x32_bf16(al.h, Bh.h, acc, 0, 0, 0);
        }
        #pragma unroll
        for (int r = 0; r < 4; r++) {
            int po = tile*16 + g*4 + r;
            float v = acc[r];
            y3[(size_t)po*64 + ft*16 + sidx] = v;
            s0a += v;
            s1a = fmaf(v, v, s1a);
        }
    }
    s0a += __shfl_xor(s0a, 16, 64); s0a += __shfl_xor(s0a, 32, 64);
    s1a += __shfl_xor(s1a, 16, 64); s1a += __shfl_xor(s1a, 32, 64);
    __shared__ float r0[64], r1[64];
    if (l < 16) { r0[wv*16 + sidx] = s0a; r1[wv*16 + sidx] = s1a; }
    __syncthreads();
    int tid = threadIdx.x;
    if (tid < 64) {
        atomicAdd(&stats[SUM3 + tid], r0[tid]);
        atomicAdd(&stats[SSQ3 + tid], r1[tid]);
    }
}

// final: out = relu(bn3(y3)) in-place (layer 1 only).
__global__ void k6(float* y3, const float* stats, const float* go, const float* bo) {
    int i = blockIdx.x * 256 + threadIdx.x;
    int f = i & 63;
    const float inv = 1.0f / (float)NPTS;
    float m = stats[SUM3 + f] * inv;
    float v = fmaxf(stats[SSQ3 + f] * inv - m*m, 0.0f);
    float s = go[f] * rsqrtf(v + EPSV);
    float sh = fmaf(-m, s, bo[f]);
    y3[i] = fmaxf(fmaf(s, y3[i], sh), 0.0f);
}

extern "C" void kernel_launch(void* const* d_in, const int* in_sizes, int n_in,
                              void* d_out, int out_size, void* d_ws, size_t ws_size,
                              hipStream_t stream) {
    const float* xyz    = (const float*)d_in[0];
    const float* feats0 = (const float*)d_in[1];
    const int*   knn    = (const int*)d_in[2];
    const void*  empty  = d_in[3];
    float* ws = (float*)d_ws;
    const size_t N64 = (size_t)NPTS * 64;
    unsigned short* KAb = (unsigned short*)ws;     // bf16 KA (uses half the region)
    float* QBA   = ws + N64;
    float* Y2MAX = ws + 2*N64;
    float* Y2MIN = ws + 3*N64;
    float* stats = ws + 4*N64;           // 2 x 512 floats
    float* wfold = stats + 1024;         // WFOLD_FLOATS
    uint8_t* mask = (uint8_t*)(wfold + WFOLD_FLOATS);
    float* out = (float*)d_out;

    hipMemsetAsync(stats, 0, 1024 * sizeof(float), stream);
    k_mask<<<NPTS/256, 256, 0, stream>>>((const uint32_t*)empty, mask);

    const float* const* p0 = (const float* const*)(d_in + 4);
    const float* const* p1 = (const float* const*)(d_in + 4 + 13);

    // ---- layer 0 ----
    {
        const float* const* p = p0;
        float* sl = stats;
        k0<<<16, 64, 0, stream>>>(p[0], p[1], p[2], p[3], p[4], wfold, 16);
        k1m<16, false><<<1024, 256, 0, stream>>>(feats0, xyz, p[4], wfold,
                                                 sl, p[11], p[12], KAb, QBA);
        k2<<<2048, 256, 0, stream>>>(KAb, QBA, knn, mask, sl);
        k4<<<2048, 256, 0, stream>>>(KAb, QBA, knn, mask, p[7], p[5], p[6], sl, Y2MAX, Y2MIN);
        k5m<<<2048, 256, 0, stream>>>(Y2MAX, Y2MIN, p[10], p[8], p[9], sl, out);  // y3_0 -> d_out
    }
    // ---- layer 1 ----
    {
        const float* const* p = p1;
        float* sl = stats + 512;
        k0<<<64, 64, 0, stream>>>(p[0], p[1], p[2], p[3], p[4], wfold, 64);
        k1m<64, true><<<1024, 256, 0, stream>>>(out, xyz, p[4], wfold,
                                                stats, p0[11], p0[12], KAb, QBA);
        k2<<<2048, 256, 0, stream>>>(KAb, QBA, knn, mask, sl);
        k4<<<2048, 256, 0, stream>>>(KAb, QBA, knn, mask, p[7], p[5], p[6], sl, Y2MAX, Y2MIN);
        k5m<<<2048, 256, 0, stream>>>(Y2MAX, Y2MIN, p[10], p[8], p[9], sl, out);  // y3_1 -> d_out
        k6<<<NPTS*64/256, 256, 0, stream>>>(out, sl, p[11], p[12]);               // in-place bn3
    }
}

// Round 13
// 598.436 us; speedup vs baseline: 1.0521x; 1.0521x over previous
//
#include <hip/hip_runtime.h>
#include <cstdint>

#define NPTS 65536
#define NS 16
#define EPSV 1e-5f

typedef __attribute__((ext_vector_type(8))) short bf16x8;
typedef __attribute__((ext_vector_type(8))) unsigned short u16x8;
typedef __attribute__((ext_vector_type(4))) float f32x4;
typedef __attribute__((ext_vector_type(4))) unsigned int u32x4;
union FragU { u32x4 u; bf16x8 h; };

// per-layer stats block (512 floats each)
#define SUM1 0
#define SSQ1 64
#define SUM2 128
#define SSQ2 192
#define SUM3 256
#define SSQ3 320
// wfold region (floats)
#define WKAOF 0
#define WQBAOF 4096
#define BKAOF 8192
#define BQBAOF 8256
#define WFOLD_FLOATS 8320

// truncation split of two floats into packed bf16 hi-pair / lo-pair (v_perm based).
__device__ __forceinline__ void split2(float e0, float e1, unsigned int& hi, unsigned int& lo) {
    unsigned int u0 = __float_as_uint(e0), u1 = __float_as_uint(e1);
    hi = __builtin_amdgcn_perm(u1, u0, 0x07060302u);
    float l0f = e0 - __uint_as_float(u0 & 0xFFFF0000u);
    float l1f = e1 - __uint_as_float(u1 & 0xFFFF0000u);
    lo = __builtin_amdgcn_perm(__float_as_uint(l1f), __float_as_uint(l0f), 0x07060302u);
}

// fp32 -> bf16 round-to-nearest(-even-ish)
__device__ __forceinline__ unsigned short f2bf(float x) {
    unsigned int u = __float_as_uint(x);
    u += 0x7FFFu + ((u >> 16) & 1u);
    return (unsigned short)(u >> 16);
}
__device__ __forceinline__ float bf2f(unsigned short h) {
    return __uint_as_float(((unsigned int)h) << 16);
}

__global__ void k_mask(const uint32_t* emp32, uint8_t* mask) {
    int bad = 0;
    for (int w = threadIdx.x; w < 1024; w += 256) bad |= (emp32[w] > 1u) ? 1 : 0;
    __shared__ int sbad[4];
    unsigned long long b = __ballot(bad != 0);
    if ((threadIdx.x & 63) == 0) sbad[threadIdx.x >> 6] = (b != 0ull) ? 1 : 0;
    __syncthreads();
    int flag = sbad[0] | sbad[1] | sbad[2] | sbad[3];
    int i = blockIdx.x * 256 + threadIdx.x;
    uint8_t mv;
    if (flag) mv = (((const uint8_t*)emp32)[i] != 0);
    else      mv = (emp32[i] != 0u);
    mask[i] = mv;
}

// Folded weights: Wka = wk @ A, Wqba = wq @ (B-A); biases likewise.
__global__ void k0(const float* wq, const float* bq, const float* wk, const float* bk,
                   const float* w1, float* wfold, int cin) {
    int f = threadIdx.x;
    int c = blockIdx.x;
    float a = 0.f, q = 0.f;
    for (int d = 0; d < 64; d++) {
        float A  = w1[d*64 + f];
        float Bm = w1[(67+d)*64 + f] - A;
        a = fmaf(wk[c*64 + d], A,  a);
        q = fmaf(wq[c*64 + d], Bm, q);
    }
    wfold[WKAOF  + c*64 + f] = a;
    wfold[WQBAOF + c*64 + f] = q;
    if (c == 0) {
        float ba = 0.f, bqv = 0.f;
        for (int d = 0; d < 64; d++) {
            float A  = w1[d*64 + f];
            float Bm = w1[(67+d)*64 + f] - A;
            ba  = fmaf(bk[d], A,  ba);
            bqv = fmaf(bq[d], Bm, bqv);
        }
        wfold[BKAOF  + f] = ba;
        wfold[BQBAOF + f] = bqv;
    }
}

// MFMA k1: [KA|QBA](n,128) = prebn(feats) @ Wcat(cin,128) + xyz @ Axyz(3,128) + bias.
// KA stored as bf16 (natural layout, 128B rows); QBA fp32 natural.
template<int CIN, bool PREBN>
__global__ void __launch_bounds__(256) k1m(const float* __restrict__ feats, const float* __restrict__ xyz,
                    const float* __restrict__ w1, const float* __restrict__ wfold,
                    const float* __restrict__ statsPrev, const float* __restrict__ goP,
                    const float* __restrict__ boP,
                    unsigned short* __restrict__ KAb, float* __restrict__ QBA) {
    const int l = threadIdx.x & 63;
    const int wv = threadIdx.x >> 6;
    const int sidx = l & 15;
    const int g = l >> 4;
    const int col = sidx;
    constexpr int NT = (CIN == 64) ? 2 : 1;

    unsigned int bh[NT][2][4], bl[NT][2][4];
    #pragma unroll
    for (int t = 0; t < NT; t++)
    #pragma unroll
    for (int fl = 0; fl < 2; fl++) {
        int f128 = (wv*2 + fl)*16 + col;
        const float* W = (f128 < 64) ? (wfold + WKAOF) : (wfold + WQBAOF);
        int f = (f128 < 64) ? f128 : f128 - 64;
        #pragma unroll
        for (int r = 0; r < 4; r++) {
            int c0 = t*32 + g*8 + 2*r;
            float e0 = 0.f, e1 = 0.f;
            if (CIN == 64 || g < 2) {
                e0 = W[c0*64 + f];
                e1 = W[(c0+1)*64 + f];
            }
            split2(e0, e1, bh[t][fl][r], bl[t][fl][r]);
        }
    }
    unsigned int xbh[2][4], xbl[2][4];
    float biasf[2];
    #pragma unroll
    for (int fl = 0; fl < 2; fl++) {
        int f128 = (wv*2 + fl)*16 + col;
        float A0, A1, A2;
        if (f128 < 64) {
            A0 = w1[64*64 + f128]; A1 = w1[65*64 + f128]; A2 = w1[66*64 + f128];
            biasf[fl] = wfold[BKAOF + f128];
        } else {
            int f = f128 - 64;
            A0 = w1[131*64 + f] - w1[64*64 + f];
            A1 = w1[132*64 + f] - w1[65*64 + f];
            A2 = w1[133*64 + f] - w1[66*64 + f];
            biasf[fl] = wfold[BQBAOF + f];
        }
        split2(A0, A1, xbh[fl][0], xbl[fl][0]);
        split2(A2, 0.f, xbh[fl][1], xbl[fl][1]);
        xbh[fl][2] = 0; xbh[fl][3] = 0; xbl[fl][2] = 0; xbl[fl][3] = 0;
    }
    float scP[NT*8], shP[NT*8];
    if (PREBN) {
        const float invN = 1.0f / (float)NPTS;
        #pragma unroll
        for (int t = 0; t < NT; t++)
        #pragma unroll
        for (int i = 0; i < 8; i++) {
            int c = t*32 + g*8 + i;
            float m = statsPrev[SUM3 + c] * invN;
            float v = fmaxf(statsPrev[SSQ3 + c] * invN - m*m, 0.0f);
            float s = goP[c] * rsqrtf(v + EPSV);
            scP[t*8+i] = s;
            shP[t*8+i] = fmaf(-m, s, boP[c]);
        }
    }

    for (int tile = blockIdx.x; tile < NPTS/16; tile += gridDim.x) {
        int p = tile*16 + sidx;
        unsigned int ahu[NT][4], alu[NT][4];
        #pragma unroll
        for (int t = 0; t < NT; t++) {
            float xv[8];
            if (CIN == 64) {
                f32x4 a0 = *(const f32x4*)(feats + (size_t)p*64 + t*32 + g*8);
                f32x4 a1 = *(const f32x4*)(feats + (size_t)p*64 + t*32 + g*8 + 4);
                #pragma unroll
                for (int i = 0; i < 4; i++) { xv[i] = a0[i]; xv[4+i] = a1[i]; }
                if (PREBN) {
                    #pragma unroll
                    for (int i = 0; i < 8; i++)
                        xv[i] = fmaxf(fmaf(scP[t*8+i], xv[i], shP[t*8+i]), 0.0f);
                }
            } else {
                if (g < 2) {
                    f32x4 a0 = *(const f32x4*)(feats + (size_t)p*16 + g*8);
                    f32x4 a1 = *(const f32x4*)(feats + (size_t)p*16 + g*8 + 4);
                    #pragma unroll
                    for (int i = 0; i < 4; i++) { xv[i] = a0[i]; xv[4+i] = a1[i]; }
                } else {
                    #pragma unroll
                    for (int i = 0; i < 8; i++) xv[i] = 0.f;
                }
            }
            #pragma unroll
            for (int r = 0; r < 4; r++) split2(xv[2*r], xv[2*r+1], ahu[t][r], alu[t][r]);
        }
        unsigned int xah[4] = {0,0,0,0}, xal[4] = {0,0,0,0};
        if (g == 0) {
            float x0 = xyz[p*3], x1 = xyz[p*3+1], x2 = xyz[p*3+2];
            split2(x0, x1, xah[0], xal[0]);
            split2(x2, 0.f, xah[1], xal[1]);
        }
        f32x4 acc[2];
        #pragma unroll
        for (int fl = 0; fl < 2; fl++)
            acc[fl] = (f32x4){biasf[fl], biasf[fl], biasf[fl], biasf[fl]};
        #pragma unroll
        for (int t = 0; t < NT; t++) {
            FragU ah, al;
            ah.u = (u32x4){ahu[t][0], ahu[t][1], ahu[t][2], ahu[t][3]};
            al.u = (u32x4){alu[t][0], alu[t][1], alu[t][2], alu[t][3]};
            #pragma unroll
            for (int fl = 0; fl < 2; fl++) {
                FragU Bh, Bl;
                Bh.u = (u32x4){bh[t][fl][0], bh[t][fl][1], bh[t][fl][2], bh[t][fl][3]};
                Bl.u = (u32x4){bl[t][fl][0], bl[t][fl][1], bl[t][fl][2], bl[t][fl][3]};
                acc[fl] = __builtin_amdgcn_mfma_f32_16x16x32_bf16(ah.h, Bh.h, acc[fl], 0, 0, 0);
                acc[fl] = __builtin_amdgcn_mfma_f32_16x16x32_bf16(ah.h, Bl.h, acc[fl], 0, 0, 0);
                acc[fl] = __builtin_amdgcn_mfma_f32_16x16x32_bf16(al.h, Bh.h, acc[fl], 0, 0, 0);
            }
        }
        {
            FragU ah, al;
            ah.u = (u32x4){xah[0], xah[1], xah[2], xah[3]};
            al.u = (u32x4){xal[0], xal[1], xal[2], xal[3]};
            #pragma unroll
            for (int fl = 0; fl < 2; fl++) {
                FragU Bh, Bl;
                Bh.u = (u32x4){xbh[fl][0], xbh[fl][1], xbh[fl][2], xbh[fl][3]};
                Bl.u = (u32x4){xbl[fl][0], xbl[fl][1], xbl[fl][2], xbl[fl][3]};
                acc[fl] = __builtin_amdgcn_mfma_f32_16x16x32_bf16(ah.h, Bh.h, acc[fl], 0, 0, 0);
                acc[fl] = __builtin_amdgcn_mfma_f32_16x16x32_bf16(ah.h, Bl.h, acc[fl], 0, 0, 0);
                acc[fl] = __builtin_amdgcn_mfma_f32_16x16x32_bf16(al.h, Bh.h, acc[fl], 0, 0, 0);
            }
        }
        #pragma unroll
        for (int fl = 0; fl < 2; fl++) {
            int f128 = (wv*2 + fl)*16 + col;
            #pragma unroll
            for (int r = 0; r < 4; r++) {
                int po = tile*16 + g*4 + r;
                float v = acc[fl][r];
                if (f128 < 64) KAb[(size_t)po*64 + f128] = f2bf(v);
                else           QBA[(size_t)po*64 + (f128-64)] = v;
            }
        }
    }
}

// k2: stats of y1 over (n,s). Batch-4 bf16-KA gather (2x16B/row/lane, full lines).
__global__ void __launch_bounds__(256) k2(const unsigned short* __restrict__ KAb, const float* __restrict__ QBA,
                   const int* __restrict__ knn, const uint8_t* __restrict__ mask, float* stats) {
    const int l = threadIdx.x & 63;
    const int wv = threadIdx.x >> 6;
    const int s = l & 15;
    const int g = l >> 4;
    float s0[16], s1[16];
    #pragma unroll
    for (int i = 0; i < 16; i++) { s0[i] = 0.f; s1[i] = 0.f; }

    const int STR = gridDim.x * 16;
    for (int n0 = blockIdx.x * 16 + wv*4; n0 < NPTS; n0 += STR) {
        bool msk[4];
        u16x8 ka[4][2];
        #pragma unroll
        for (int u = 0; u < 4; u++) {
            int n = n0 + u;
            msk[u] = (mask[n] != 0);
            if (!msk[u]) {
                int j = knn[n*16 + s];
                const unsigned short* kp = KAb + (size_t)j*64;
                ka[u][0] = *(const u16x8*)(kp + g*8);
                ka[u][1] = *(const u16x8*)(kp + 32 + g*8);
            }
        }
        #pragma unroll
        for (int u = 0; u < 4; u++) {
            if (msk[u]) continue;
            int n = n0 + u;
            const float* qp = QBA + (size_t)n*64;
            f32x4 q0 = *(const f32x4*)(qp + g*8);
            f32x4 q1 = *(const f32x4*)(qp + g*8 + 4);
            f32x4 q2 = *(const f32x4*)(qp + 32 + g*8);
            f32x4 q3 = *(const f32x4*)(qp + 32 + g*8 + 4);
            #pragma unroll
            for (int t = 0; t < 2; t++)
            #pragma unroll
            for (int i = 0; i < 8; i++) {
                float kf = bf2f(ka[u][t][i]);
                float qv = t ? ((i < 4) ? q2[i] : q3[i-4])
                             : ((i < 4) ? q0[i] : q1[i-4]);
                float y = kf + qv;
                s0[t*8+i] += y;
                s1[t*8+i] = fmaf(y, y, s1[t*8+i]);
            }
        }
    }
    #pragma unroll
    for (int i = 0; i < 16; i++) {
        #pragma unroll
        for (int d = 1; d < 16; d <<= 1) {
            s0[i] += __shfl_xor(s0[i], d, 64);
            s1[i] += __shfl_xor(s1[i], d, 64);
        }
    }
    __shared__ float r0[4][64], r1[4][64];
    if (s == 0) {
        #pragma unroll
        for (int t = 0; t < 2; t++)
        #pragma unroll
        for (int i = 0; i < 8; i++) {
            int c = t*32 + g*8 + i;
            r0[wv][c] = s0[t*8+i];
            r1[wv][c] = s1[t*8+i];
        }
    }
    __syncthreads();
    int tid = threadIdx.x;
    if (tid < 64) {
        atomicAdd(&stats[SUM1 + tid], r0[0][tid]+r0[1][tid]+r0[2][tid]+r0[3][tid]);
        atomicAdd(&stats[SSQ1 + tid], r1[0][tid]+r1[1][tid]+r1[2][tid]+r1[3][tid]);
    }
}

// k3: prescale (in-place): KAb *= sc1 (bf16), QBA = sc1*QBA + sh1 (fp32).
// After this, k4's bn1 is x = relu(KAb' + QBA') (masked: relu(sh1)).
__global__ void __launch_bounds__(256) k3(unsigned short* KAb, float* QBA,
                   const float* __restrict__ stats, const float* __restrict__ g1,
                   const float* __restrict__ b1) {
    int t = blockIdx.x * 256 + threadIdx.x;      // [0, NPTS*8)
    int n = t >> 3, c8 = (t & 7) * 8;
    const float inv = 1.0f / ((float)NPTS * (float)NS);
    float sc[8], sh[8];
    #pragma unroll
    for (int i = 0; i < 8; i++) {
        int c = c8 + i;
        float m = stats[SUM1 + c] * inv;
        float v = fmaxf(stats[SSQ1 + c] * inv - m*m, 0.0f);
        float s = g1[c] * rsqrtf(v + EPSV);
        sc[i] = s;
        sh[i] = fmaf(-m, s, b1[c]);
    }
    u16x8 ka = *(const u16x8*)(KAb + (size_t)n*64 + c8);
    #pragma unroll
    for (int i = 0; i < 8; i++) ka[i] = f2bf(sc[i] * bf2f(ka[i]));
    *(u16x8*)(KAb + (size_t)n*64 + c8) = ka;
    f32x4 qa = *(const f32x4*)(QBA + (size_t)n*64 + c8);
    f32x4 qb = *(const f32x4*)(QBA + (size_t)n*64 + c8 + 4);
    #pragma unroll
    for (int i = 0; i < 4; i++) {
        qa[i] = fmaf(sc[i],   qa[i], sh[i]);
        qb[i] = fmaf(sc[4+i], qb[i], sh[4+i]);
    }
    *(f32x4*)(QBA + (size_t)n*64 + c8)     = qa;
    *(f32x4*)(QBA + (size_t)n*64 + c8 + 4) = qb;
}

// MFMA k4: batch-2 bf16 prescaled gather -> x = relu(ka'+qb') -> x @ w2 (3-term split),
// stats2 + per-(n,f) max/min. No sc1v/sh1v arrays (prescaled); masked x = xm.
__global__ void __launch_bounds__(256) k4(const unsigned short* __restrict__ KAb, const float* __restrict__ QBA,
                   const int* __restrict__ knn, const uint8_t* __restrict__ mask,
                   const float* __restrict__ w2, const float* __restrict__ g1, const float* __restrict__ b1,
                   float* stats, float* __restrict__ y2max, float* __restrict__ y2min) {
    const int l    = threadIdx.x & 63;
    const int wv   = threadIdx.x >> 6;
    const int sidx = l & 15;
    const int g    = l >> 4;
    const int col  = sidx;

    // masked-point x: relu(sh1[c]) for channels c = t*32 + g*8 + i
    float xm[16];
    const float inv = 1.0f / ((float)NPTS * (float)NS);
    #pragma unroll
    for (int t = 0; t < 2; t++)
    #pragma unroll
    for (int i = 0; i < 8; i++) {
        int c = t*32 + g*8 + i;
        float m = stats[SUM1 + c] * inv;
        float v = fmaxf(stats[SSQ1 + c] * inv - m*m, 0.0f);
        float s = g1[c] * rsqrtf(v + EPSV);
        xm[t*8+i] = fmaxf(fmaf(-m, s, b1[c]), 0.0f);
    }

    unsigned int whu[2][4][4], wlu[2][4][4];
    #pragma unroll
    for (int t = 0; t < 2; t++)
    #pragma unroll
    for (int ft = 0; ft < 4; ft++)
    #pragma unroll
    for (int r = 0; r < 4; r++) {
        int k0i = t*32 + g*8 + 2*r;
        float e0 = w2[k0i*64 + ft*16 + col];
        float e1 = w2[(k0i+1)*64 + ft*16 + col];
        split2(e0, e1, whu[t][ft][r], wlu[t][ft][r]);
    }

    float s0t[4] = {0.f,0.f,0.f,0.f};
    float s1t[4] = {0.f,0.f,0.f,0.f};

    const int STR = gridDim.x * 8;
    for (int n0 = blockIdx.x * 8 + wv*2; n0 < NPTS; n0 += STR) {
        bool msk[2];
        u16x8 ka[2][2];
        #pragma unroll
        for (int u = 0; u < 2; u++) {
            int n = n0 + u;
            msk[u] = (mask[n] != 0);
            int j = knn[n*16 + sidx];
            const unsigned short* kp = KAb + (size_t)j*64;
            ka[u][0] = *(const u16x8*)(kp + g*8);
            ka[u][1] = *(const u16x8*)(kp + 32 + g*8);
        }
        #pragma unroll
        for (int u = 0; u < 2; u++) {
            int n = n0 + u;
            bool masked = msk[u];
            const float* qp = QBA + (size_t)n*64;
            f32x4 q0 = *(const f32x4*)(qp + g*8);
            f32x4 q1 = *(const f32x4*)(qp + g*8 + 4);
            f32x4 q2 = *(const f32x4*)(qp + 32 + g*8);
            f32x4 q3 = *(const f32x4*)(qp + 32 + g*8 + 4);

            float x[16];
            #pragma unroll
            for (int t = 0; t < 2; t++)
            #pragma unroll
            for (int i = 0; i < 8; i++) {
                float kf = bf2f(ka[u][t][i]);
                float qv = t ? ((i < 4) ? q2[i] : q3[i-4])
                             : ((i < 4) ? q0[i] : q1[i-4]);
                x[t*8+i] = masked ? xm[t*8+i] : fmaxf(kf + qv, 0.0f);
            }

            unsigned int ahu[2][4], alu[2][4];
            #pragma unroll
            for (int t = 0; t < 2; t++)
            #pragma unroll
            for (int r = 0; r < 4; r++)
                split2(x[t*8 + 2*r], x[t*8 + 2*r + 1], ahu[t][r], alu[t][r]);

            f32x4 acc[4];
            #pragma unroll
            for (int ft = 0; ft < 4; ft++) acc[ft] = (f32x4){0.f,0.f,0.f,0.f};

            #pragma unroll
            for (int t = 0; t < 2; t++) {
                FragU ah, al;
                ah.u = (u32x4){ahu[t][0], ahu[t][1], ahu[t][2], ahu[t][3]};
                al.u = (u32x4){alu[t][0], alu[t][1], alu[t][2], alu[t][3]};
                #pragma unroll
                for (int ft = 0; ft < 4; ft++) {
                    FragU bhf, blf;
                    bhf.u = (u32x4){whu[t][ft][0], whu[t][ft][1], whu[t][ft][2], whu[t][ft][3]};
                    blf.u = (u32x4){wlu[t][ft][0], wlu[t][ft][1], wlu[t][ft][2], wlu[t][ft][3]};
                    acc[ft] = __builtin_amdgcn_mfma_f32_16x16x32_bf16(ah.h, bhf.h, acc[ft], 0, 0, 0);
                    acc[ft] = __builtin_amdgcn_mfma_f32_16x16x32_bf16(ah.h, blf.h, acc[ft], 0, 0, 0);
                    acc[ft] = __builtin_amdgcn_mfma_f32_16x16x32_bf16(al.h, bhf.h, acc[ft], 0, 0, 0);
                }
            }

            float tmax[4], tmin[4];
            #pragma unroll
            for (int ft = 0; ft < 4; ft++) {
                f32x4 d = acc[ft];
                float lmax = fmaxf(fmaxf(d[0], d[1]), fmaxf(d[2], d[3]));
                float lmin = fminf(fminf(d[0], d[1]), fminf(d[2], d[3]));
                s0t[ft] += (d[0] + d[1]) + (d[2] + d[3]);
                s1t[ft] += fmaf(d[0],d[0], fmaf(d[1],d[1], fmaf(d[2],d[2], d[3]*d[3])));
                lmax = fmaxf(lmax, __shfl_xor(lmax, 16, 64));
                lmax = fmaxf(lmax, __shfl_xor(lmax, 32, 64));
                lmin = fminf(lmin, __shfl_xor(lmin, 16, 64));
                lmin = fminf(lmin, __shfl_xor(lmin, 32, 64));
                tmax[ft] = lmax; tmin[ft] = lmin;
            }
            float mx = (g==0) ? tmax[0] : (g==1) ? tmax[1] : (g==2) ? tmax[2] : tmax[3];
            float mn = (g==0) ? tmin[0] : (g==1) ? tmin[1] : (g==2) ? tmin[2] : tmin[3];
            y2max[(size_t)n*64 + l] = mx;
            y2min[(size_t)n*64 + l] = mn;
        }
    }

    #pragma unroll
    for (int ft = 0; ft < 4; ft++) {
        s0t[ft] += __shfl_xor(s0t[ft], 16, 64);
        s0t[ft] += __shfl_xor(s0t[ft], 32, 64);
        s1t[ft] += __shfl_xor(s1t[ft], 16, 64);
        s1t[ft] += __shfl_xor(s1t[ft], 32, 64);
    }
    float myS0 = (g==0) ? s0t[0] : (g==1) ? s0t[1] : (g==2) ? s0t[2] : s0t[3];
    float myS1 = (g==0) ? s1t[0] : (g==1) ? s1t[1] : (g==2) ? s1t[2] : s1t[3];
    __shared__ float red[8][64];
    red[wv][l] = myS0;
    red[4+wv][l] = myS1;
    __syncthreads();
    if (wv == 0) {
        atomicAdd(&stats[SUM2 + l], red[0][l]+red[1][l]+red[2][l]+red[3][l]);
        atomicAdd(&stats[SSQ2 + l], red[4][l]+red[5][l]+red[6][l]+red[7][l]);
    }
}

// MFMA k5: m = relu(bn2(max/min)); y3 = m @ wo; stats3.  y2min read only if any
// channel has negative bn2 scale (wave-uniform ballot).
__global__ void __launch_bounds__(256) k5m(const float* __restrict__ y2max, const float* __restrict__ y2min,
                    const float* __restrict__ wo, const float* __restrict__ g2, const float* __restrict__ b2,
                    float* stats, float* __restrict__ y3) {
    const int l = threadIdx.x & 63;
    const int wv = threadIdx.x >> 6;
    const int sidx = l & 15;
    const int g = l >> 4;
    const int ft = wv;

    unsigned int bh[2][4], bl[2][4];
    #pragma unroll
    for (int t = 0; t < 2; t++)
    #pragma unroll
    for (int r = 0; r < 4; r++) {
        int c0 = t*32 + g*8 + 2*r;
        split2(wo[c0*64 + ft*16 + sidx], wo[(c0+1)*64 + ft*16 + sidx], bh[t][r], bl[t][r]);
    }
    float sc2v[16], sh2v[16];
    const float inv = 1.0f / ((float)NPTS * (float)NS);
    int anyneg = 0;
    #pragma unroll
    for (int t = 0; t < 2; t++)
    #pragma unroll
    for (int i = 0; i < 8; i++) {
        int c = t*32 + g*8 + i;
        float m = stats[SUM2 + c] * inv;
        float v = fmaxf(stats[SSQ2 + c] * inv - m*m, 0.0f);
        float s = g2[c] * rsqrtf(v + EPSV);
        sc2v[t*8+i] = s;
        sh2v[t*8+i] = fmaf(-m, s, b2[c]);
        anyneg |= (s < 0.0f) ? 1 : 0;
    }
    const bool need_mn = (__ballot(anyneg != 0) != 0ull);

    float s0a = 0.f, s1a = 0.f;
    for (int tile = blockIdx.x; tile < NPTS/16; tile += gridDim.x) {
        int p = tile*16 + sidx;
        unsigned int ahu[2][4], alu[2][4];
        #pragma unroll
        for (int t = 0; t < 2; t++) {
            f32x4 mx0 = *(const f32x4*)(y2max + (size_t)p*64 + t*32 + g*8);
            f32x4 mx1 = *(const f32x4*)(y2max + (size_t)p*64 + t*32 + g*8 + 4);
            f32x4 mn0 = mx0, mn1 = mx1;
            if (need_mn) {
                mn0 = *(const f32x4*)(y2min + (size_t)p*64 + t*32 + g*8);
                mn1 = *(const f32x4*)(y2min + (size_t)p*64 + t*32 + g*8 + 4);
            }
            float mval[8];
            #pragma unroll
            for (int i = 0; i < 4; i++) {
                float sc = sc2v[t*8+i];
                float pre = (sc >= 0.f) ? mx0[i] : mn0[i];
                mval[i] = fmaxf(fmaf(sc, pre, sh2v[t*8+i]), 0.0f);
                float sc2 = sc2v[t*8+4+i];
                float pre2 = (sc2 >= 0.f) ? mx1[i] : mn1[i];
                mval[4+i] = fmaxf(fmaf(sc2, pre2, sh2v[t*8+4+i]), 0.0f);
            }
            #pragma unroll
            for (int r = 0; r < 4; r++) split2(mval[2*r], mval[2*r+1], ahu[t][r], alu[t][r]);
        }
        f32x4 acc = (f32x4){0.f,0.f,0.f,0.f};
        #pragma unroll
        for (int t = 0; t < 2; t++) {
            FragU ah, al, Bh, Bl;
            ah.u = (u32x4){ahu[t][0], ahu[t][1], ahu[t][2], ahu[t][3]};
            al.u = (u32x4){alu[t][0], alu[t][1], alu[t][2], alu[t][3]};
            Bh.u = (u32x4){bh[t][0], bh[t][1], bh[t][2], bh[t][3]};
            Bl.u = (u32x4){bl[t][0], bl[t][1], bl[t][2], bl[t][3]};
            acc = __builtin_amdgcn_mfma_f32_16x16x32_bf16(ah.h, Bh.h, acc, 0, 0, 0);
            acc = __builtin_amdgcn_mfma_f32_16x16x32_bf16(ah.h, Bl.h, acc, 0, 0, 0);
            acc = __builtin_amdgcn_mfma_f32_16x16x32_bf16(al.h, Bh.h, acc, 0, 0, 0);
        }
        #pragma unroll
        for (int r = 0; r < 4; r++) {
            int po = tile*16 + g*4 + r;
            float v = acc[r];
            y3[(size_t)po*64 + ft*16 + sidx] = v;
            s0a += v;
            s1a = fmaf(v, v, s1a);
        }
    }
    s0a += __shfl_xor(s0a, 16, 64); s0a += __shfl_xor(s0a, 32, 64);
    s1a += __shfl_xor(s1a, 16, 64); s1a += __shfl_xor(s1a, 32, 64);
    __shared__ float r0[64], r1[64];
    if (l < 16) { r0[wv*16 + sidx] = s0a; r1[wv*16 + sidx] = s1a; }
    __syncthreads();
    int tid = threadIdx.x;
    if (tid < 64) {
        atomicAdd(&stats[SUM3 + tid], r0[tid]);
        atomicAdd(&stats[SSQ3 + tid], r1[tid]);
    }
}

// final: out = relu(bn3(y3)) in-place (layer 1 only).
__global__ void k6(float* y3, const float* stats, const float* go, const float* bo) {
    int i = blockIdx.x * 256 + threadIdx.x;
    int f = i & 63;
    const float inv = 1.0f / (float)NPTS;
    float m = stats[SUM3 + f] * inv;
    float v = fmaxf(stats[SSQ3 + f] * inv - m*m, 0.0f);
    float s = go[f] * rsqrtf(v + EPSV);
    float sh = fmaf(-m, s, bo[f]);
    y3[i] = fmaxf(fmaf(s, y3[i], sh), 0.0f);
}

extern "C" void kernel_launch(void* const* d_in, const int* in_sizes, int n_in,
                              void* d_out, int out_size, void* d_ws, size_t ws_size,
                              hipStream_t stream) {
    const float* xyz    = (const float*)d_in[0];
    const float* feats0 = (const float*)d_in[1];
    const int*   knn    = (const int*)d_in[2];
    const void*  empty  = d_in[3];
    float* ws = (float*)d_ws;
    const size_t N64 = (size_t)NPTS * 64;
    unsigned short* KAb = (unsigned short*)ws;     // bf16 KA (uses half the region)
    float* QBA   = ws + N64;
    float* Y2MAX = ws + 2*N64;
    float* Y2MIN = ws + 3*N64;
    float* stats = ws + 4*N64;           // 2 x 512 floats
    float* wfold = stats + 1024;         // WFOLD_FLOATS
    uint8_t* mask = (uint8_t*)(wfold + WFOLD_FLOATS);
    float* out = (float*)d_out;

    hipMemsetAsync(stats, 0, 1024 * sizeof(float), stream);
    k_mask<<<NPTS/256, 256, 0, stream>>>((const uint32_t*)empty, mask);

    const float* const* p0 = (const float* const*)(d_in + 4);
    const float* const* p1 = (const float* const*)(d_in + 4 + 13);

    // ---- layer 0 ----
    {
        const float* const* p = p0;
        float* sl = stats;
        k0<<<16, 64, 0, stream>>>(p[0], p[1], p[2], p[3], p[4], wfold, 16);
        k1m<16, false><<<1024, 256, 0, stream>>>(feats0, xyz, p[4], wfold,
                                                 sl, p[11], p[12], KAb, QBA);
        k2<<<2048, 256, 0, stream>>>(KAb, QBA, knn, mask, sl);
        k3<<<NPTS*8/256, 256, 0, stream>>>(KAb, QBA, sl, p[5], p[6]);
        k4<<<2048, 256, 0, stream>>>(KAb, QBA, knn, mask, p[7], p[5], p[6], sl, Y2MAX, Y2MIN);
        k5m<<<2048, 256, 0, stream>>>(Y2MAX, Y2MIN, p[10], p[8], p[9], sl, out);  // y3_0 -> d_out
    }
    // ---- layer 1 ----
    {
        const float* const* p = p1;
        float* sl = stats + 512;
        k0<<<64, 64, 0, stream>>>(p[0], p[1], p[2], p[3], p[4], wfold, 64);
        k1m<64, true><<<1024, 256, 0, stream>>>(out, xyz, p[4], wfold,
                                                stats, p0[11], p0[12], KAb, QBA);
        k2<<<2048, 256, 0, stream>>>(KAb, QBA, knn, mask, sl);
        k3<<<NPTS*8/256, 256, 0, stream>>>(KAb, QBA, sl, p[5], p[6]);
        k4<<<2048, 256, 0, stream>>>(KAb, QBA, knn, mask, p[7], p[5], p[6], sl, Y2MAX, Y2MIN);
        k5m<<<2048, 256, 0, stream>>>(Y2MAX, Y2MIN, p[10], p[8], p[9], sl, out);  // y3_1 -> d_out
        k6<<<NPTS*64/256, 256, 0, stream>>>(out, sl, p[11], p[12]);               // in-place bn3
    }
}